// Round 1
// baseline (169.354 us; speedup 1.0000x reference)
//
#include <hip/hip_runtime.h>
#include <math.h>

// Problem constants (reference: N=64, H=512, W=512, RATIO=2, ITERATIONS=1)
#define NIMG 64
#define HH 512
#define WW 512
#define TR 8                      // output rows per block
#define ROWSTRIDE 520             // LDS bytes per staged row (>=516, %4==0)
#define LROWS (TR + 2)            // staged rows incl. vertical halo
#define NBLOCKS (NIMG * (HH / TR))   // 64*64 = 4096
#define INV_TOTAL (1.0f / 16777216.0f)  // 1/(64*512*512), exact pow2

// Flag byte per pixel: bit0 = (y>0), bit1 = (y==0), 0x00 = invalid/halo.
// border(pixel) = window-OR has both bits set.
__global__ __launch_bounds__(256) void border_loss_main(
    const float* __restrict__ x, const int* __restrict__ y,
    float* __restrict__ part, int atomic_mode)
{
    __shared__ unsigned char flags[LROWS * ROWSTRIDE];
    __shared__ float wsum[4];

    const int tid = threadIdx.x;
    const int nb  = blockIdx.x;
    const int n   = nb >> 6;                 // image index (64 stripes per image)
    const int R0  = (nb & 63) * TR;          // first output row of this stripe
    const long long imgbase = (long long)n * HH * WW;

    // Zero halo bytes: col -1 at offset 0; cols 512..514 region at 513..515.
    if (tid < LROWS) {
        unsigned char* row = &flags[tid * ROWSTRIDE];
        row[0] = 0; row[513] = 0; row[514] = 0; row[515] = 0;
    }

    // Stage flags: 10 rows x 128 int4-groups = 1280 tasks over 256 threads.
    #pragma unroll
    for (int it = 0; it < 5; ++it) {
        int idx = tid + it * 256;
        int j = idx >> 7;                    // LDS row 0..9  (global row R0-1+j)
        int g = idx & 127;                   // 4-pixel group
        int gr = R0 - 1 + j;
        unsigned int f4 = 0;                 // invalid rows stay all-zero
        if ((unsigned)gr < (unsigned)HH) {
            const int4 yv = *(const int4*)(y + imgbase + (long long)gr * WW + 4 * g);
            f4  = (yv.x > 0 ? 1u : 2u);
            f4 |= (yv.y > 0 ? 1u : 2u) << 8;
            f4 |= (yv.z > 0 ? 1u : 2u) << 16;
            f4 |= (yv.w > 0 ? 1u : 2u) << 24;
        }
        // col c lives at byte offset c+1 -> group starts at 4g+1 (unaligned; byte stores)
        unsigned char* p = &flags[j * ROWSTRIDE + 4 * g + 1];
        p[0] = (unsigned char)(f4);
        p[1] = (unsigned char)(f4 >> 8);
        p[2] = (unsigned char)(f4 >> 16);
        p[3] = (unsigned char)(f4 >> 24);
    }
    __syncthreads();

    float acc = 0.0f;

    // Compute: 8 rows x 128 groups = 1024 tasks over 256 threads.
    #pragma unroll
    for (int it = 0; it < 4; ++it) {
        int idx = tid + it * 256;
        int r = idx >> 7;                    // output row offset 0..7
        int g = idx & 127;
        // LDS rows r, r+1, r+2 == global rows (R0+r-1 .. R0+r+1).
        // Aligned u32 reads at byte offset 4g cover cols 4g-1 .. 4g+6.
        const unsigned int* l0 = (const unsigned int*)&flags[(r    ) * ROWSTRIDE + 4 * g];
        const unsigned int* l1 = (const unsigned int*)&flags[(r + 1) * ROWSTRIDE + 4 * g];
        const unsigned int* l2 = (const unsigned int*)&flags[(r + 2) * ROWSTRIDE + 4 * g];
        unsigned long long v0 = (unsigned long long)l0[0] | ((unsigned long long)l0[1] << 32);
        unsigned long long v1 = (unsigned long long)l1[0] | ((unsigned long long)l1[1] << 32);
        unsigned long long v2 = (unsigned long long)l2[0] | ((unsigned long long)l2[1] << 32);
        unsigned long long v = v0 | v1 | v2;           // vertical OR, bytes = cols 4g-1..4g+6
        unsigned long long h = v | (v >> 8) | (v >> 16); // h byte k = OR of cols 4g+k-1..4g+k+1

        const float4 xv = *(const float4*)(x + imgbase + (long long)(R0 + r) * WW + 4 * g);
        const float xs[4] = {xv.x, xv.y, xv.z, xv.w};
        #pragma unroll
        for (int k = 0; k < 4; ++k) {
            float xf = xs[k];
            // center mask bit: row r+1, col 4g+k -> byte k+1 of v1
            float m = (float)((unsigned)(v1 >> (8 * (k + 1))) & 1u);
            float l = fmaxf(xf, 0.0f) - xf * m + log1pf(expf(-fabsf(xf)));
            float wgt = (((unsigned)(h >> (8 * k)) & 3u) == 3u) ? 2.0f : 1.0f;
            acc += l * wgt;
        }
    }

    // Block reduction: wave shuffle (width 64) + LDS across 4 waves.
    #pragma unroll
    for (int off = 32; off > 0; off >>= 1)
        acc += __shfl_down(acc, off);
    if ((tid & 63) == 0) wsum[tid >> 6] = acc;
    __syncthreads();
    if (tid == 0) {
        float s = wsum[0] + wsum[1] + wsum[2] + wsum[3];
        if (atomic_mode) atomicAdd(part, s * INV_TOTAL);
        else             part[blockIdx.x] = s;
    }
}

__global__ __launch_bounds__(256) void border_loss_reduce(
    const float* __restrict__ part, float* __restrict__ out)
{
    __shared__ float wsum[4];
    float s = 0.0f;
    for (int i = threadIdx.x; i < NBLOCKS; i += 256) s += part[i];
    #pragma unroll
    for (int off = 32; off > 0; off >>= 1)
        s += __shfl_down(s, off);
    if ((threadIdx.x & 63) == 0) wsum[threadIdx.x >> 6] = s;
    __syncthreads();
    if (threadIdx.x == 0)
        out[0] = (wsum[0] + wsum[1] + wsum[2] + wsum[3]) * INV_TOTAL;
}

__global__ void border_loss_zero(float* out) { out[0] = 0.0f; }

extern "C" void kernel_launch(void* const* d_in, const int* in_sizes, int n_in,
                              void* d_out, int out_size, void* d_ws, size_t ws_size,
                              hipStream_t stream)
{
    const float* x = (const float*)d_in[0];
    const int*   y = (const int*)d_in[1];
    float* out = (float*)d_out;

    if (ws_size >= (size_t)NBLOCKS * sizeof(float)) {
        // Deterministic two-stage reduction via workspace partials.
        float* part = (float*)d_ws;
        border_loss_main<<<NBLOCKS, 256, 0, stream>>>(x, y, part, 0);
        border_loss_reduce<<<1, 256, 0, stream>>>(part, out);
    } else {
        // Fallback: zero output then atomic accumulation.
        border_loss_zero<<<1, 1, 0, stream>>>(out);
        border_loss_main<<<NBLOCKS, 256, 0, stream>>>(x, y, out, 1);
    }
}

// Round 2
// 163.988 us; speedup vs baseline: 1.0327x; 1.0327x over previous
//
#include <hip/hip_runtime.h>
#include <math.h>

// Problem constants (reference: N=64, H=512, W=512, RATIO=2, ITERATIONS=1)
#define NIMG 64
#define HH 512
#define WW 512
#define TR 32                        // output rows per block
#define NSEG 8                       // 512 / 64 column segments
#define LROWS (TR + 2)               // staged mask rows incl. vertical halo
#define NBLOCKS (NIMG * (HH / TR))   // 64*16 = 1024
#define INV_TOTAL (1.0f / 16777216.0f)  // 1/(64*512*512), exact pow2

// Morphology on a binary mask with cv2-style border semantics reduces to:
//   ero = !window_has_zero(valid window), dil = window_has_one(valid window)
//   border = dil - ero = window_has_one & window_has_zero
// We keep per-row-segment 64-bit masks: mm = bit per col (y>0), mz = (y==0),
// with out-of-image rows/cols contributing 0 to BOTH (matches +/-inf pad).
__global__ __launch_bounds__(512) void border_loss_main(
    const float* __restrict__ x, const int* __restrict__ y,
    float* __restrict__ part, int atomic_mode)
{
    __shared__ unsigned long long mm[LROWS][NSEG];
    __shared__ unsigned long long mz[LROWS][NSEG];
    __shared__ float wsum[8];

    const int tid  = threadIdx.x;
    const int lane = tid & 63;
    const int w    = tid >> 6;               // wave 0..7
    const int nb   = blockIdx.x;
    const int n    = nb >> 4;                // image index (16 stripes/image)
    const int R0   = (nb & 15) * TR;         // first output row of stripe
    const long long imgbase = (long long)n * HH * WW;

    // ---- Phase 1: build masks for rows R0-1 .. R0+TR (LROWS x NSEG tasks).
    // Task T -> (LDS row j = T>>3, segment s = T&7). 272 tasks / 8 waves = 34
    // uniform iterations; one coalesced y-load + one ballot each.
    for (int T = w; T < LROWS * NSEG; T += 8) {
        int j = T >> 3;
        int s = T & 7;
        int gr = R0 - 1 + j;
        unsigned long long bm = 0ull, bz = 0ull;
        if ((unsigned)gr < (unsigned)HH) {   // row-uniform branch
            int yv = y[imgbase + (long long)gr * WW + (s << 6) + lane];
            bm = __ballot(yv > 0);
            bz = ~bm;                        // all 64 lanes active
        }
        if (lane == 0) { mm[j][s] = bm; mz[j][s] = bz; }
    }
    __syncthreads();

    // ---- Phase 2: sweep segments with a 3-wide vertical-OR pipeline.
    float acc = 0.0f;
    #pragma unroll
    for (int k = 0; k < TR / 8; ++k) {
        int rr = w + (k << 3);               // row offset 0..TR-1
        int jr = rr + 1;                     // LDS center row
        const float* xrow = x + imgbase + (long long)(R0 + rr) * WW;

        unsigned long long vm_prev = 0ull, vz_prev = 0ull;
        unsigned long long vm_cur = mm[jr-1][0] | mm[jr][0] | mm[jr+1][0];
        unsigned long long vz_cur = mz[jr-1][0] | mz[jr][0] | mz[jr+1][0];

        #pragma unroll
        for (int s = 0; s < NSEG; ++s) {
            unsigned long long vm_next = 0ull, vz_next = 0ull;
            if (s + 1 < NSEG) {
                vm_next = mm[jr-1][s+1] | mm[jr][s+1] | mm[jr+1][s+1];
                vz_next = mz[jr-1][s+1] | mz[jr][s+1] | mz[jr+1][s+1];
            }
            // horizontal 3-window OR with cross-segment carry bits
            unsigned long long hm = vm_cur | (vm_cur << 1) | (vm_cur >> 1)
                                  | (vm_prev >> 63) | (vm_next << 63);
            unsigned long long hz = vz_cur | (vz_cur << 1) | (vz_cur >> 1)
                                  | (vz_prev >> 63) | (vz_next << 63);
            unsigned long long border = hm & hz;
            unsigned long long mrow   = mm[jr][s];

            float xf = xrow[(s << 6) + lane];
            float a  = fabsf(xf);
            // ln(1+e^{-|x|}) via hardware v_exp_f32 / v_log_f32
            float lg = __logf(1.0f + __expf(-a));
            float mterm = ((mrow >> lane) & 1ull) ? xf : 0.0f;
            float loss  = fmaxf(xf, 0.0f) - mterm + lg;
            float wgt   = ((border >> lane) & 1ull) ? 2.0f : 1.0f;
            acc = fmaf(loss, wgt, acc);

            vm_prev = vm_cur; vz_prev = vz_cur;
            vm_cur  = vm_next; vz_cur  = vz_next;
        }
    }

    // ---- Block reduction: wave shuffle + LDS across 8 waves.
    #pragma unroll
    for (int off = 32; off > 0; off >>= 1)
        acc += __shfl_down(acc, off);
    __syncthreads();                 // mm/mz no longer needed
    if (lane == 0) wsum[w] = acc;
    __syncthreads();
    if (tid == 0) {
        float s = 0.0f;
        #pragma unroll
        for (int i = 0; i < 8; ++i) s += wsum[i];
        if (atomic_mode) atomicAdd(part, s * INV_TOTAL);
        else             part[blockIdx.x] = s;
    }
}

__global__ __launch_bounds__(256) void border_loss_reduce(
    const float* __restrict__ part, float* __restrict__ out)
{
    __shared__ float wsum[4];
    float s = 0.0f;
    for (int i = threadIdx.x; i < NBLOCKS; i += 256) s += part[i];
    #pragma unroll
    for (int off = 32; off > 0; off >>= 1)
        s += __shfl_down(s, off);
    if ((threadIdx.x & 63) == 0) wsum[threadIdx.x >> 6] = s;
    __syncthreads();
    if (threadIdx.x == 0)
        out[0] = (wsum[0] + wsum[1] + wsum[2] + wsum[3]) * INV_TOTAL;
}

__global__ void border_loss_zero(float* out) { out[0] = 0.0f; }

extern "C" void kernel_launch(void* const* d_in, const int* in_sizes, int n_in,
                              void* d_out, int out_size, void* d_ws, size_t ws_size,
                              hipStream_t stream)
{
    const float* x = (const float*)d_in[0];
    const int*   y = (const int*)d_in[1];
    float* out = (float*)d_out;

    if (ws_size >= (size_t)NBLOCKS * sizeof(float)) {
        // Deterministic two-stage reduction via workspace partials.
        float* part = (float*)d_ws;
        border_loss_main<<<NBLOCKS, 512, 0, stream>>>(x, y, part, 0);
        border_loss_reduce<<<1, 256, 0, stream>>>(part, out);
    } else {
        // Fallback: zero output then atomic accumulation.
        border_loss_zero<<<1, 1, 0, stream>>>(out);
        border_loss_main<<<NBLOCKS, 512, 0, stream>>>(x, y, out, 1);
    }
}